// Round 1
// baseline (707.397 us; speedup 1.0000x reference)
//
#include <hip/hip_runtime.h>
#include <hip/hip_fp16.h>

// Problem constants (from reference setup_inputs)
constexpr int B  = 16;
constexpr int C  = 64;
constexpr int OH = 128;
constexpr int OW = 128;
constexpr int HW = OH * OW;                 // 16384 inputs per (b,c) plane
constexpr int K  = 4;
constexpr int P  = 4;
constexpr int TAPS = HW * K * P;            // 262144 static taps
constexpr int OUT_H = 256;
constexpr int OUT_W = 256;
constexpr int PLANE = OUT_H * OUT_W;        // 65536 outputs per (b,c) plane
constexpr int NQ = 4;                       // quarters (fallback path)
constexpr int QUARTER = PLANE / NQ;
constexpr int BLOCK = 512;
constexpr size_t TABLE_BYTES = (size_t)HW * K * 16;  // 1 MiB compact table (fallback)

// Gather-path workspace layout (u32 slots):
//   offs   : PLANE+1 (padded to 65792)
//   cursor : PLANE
//   counts : PLANE
//   entries: TAPS
constexpr size_t OFFS_SLOTS   = 65792;      // 65537 rounded up
constexpr size_t WS_GATHER_BYTES =
    (OFFS_SLOTS + (size_t)PLANE + (size_t)PLANE + (size_t)TAPS) * 4;

static __device__ __forceinline__ float h2f(unsigned short u) {
    __half h; __builtin_memcpy(&h, &u, 2); return __half2float(h);
}

// ---------------- Gather pre-pass (static per launch) ----------------

__global__ __launch_bounds__(256) void zero_counts_kernel(unsigned* __restrict__ counts) {
    int r = blockIdx.x * 256 + threadIdx.x;
    if (r < PLANE) counts[r] = 0u;
}

__global__ __launch_bounds__(256) void hist_kernel(
    const int* __restrict__ sm, unsigned* __restrict__ counts)
{
    int r = blockIdx.x * 256 + threadIdx.x;
    if (r < TAPS) atomicAdd(&counts[sm[r]], 1u);
}

// Exclusive scan over 65536 counts -> offs[0..65536], cursor = offs copy.
__global__ __launch_bounds__(1024) void scan_kernel(
    const unsigned* __restrict__ counts,
    unsigned* __restrict__ offs, unsigned* __restrict__ cursor)
{
    __shared__ unsigned part[1024];
    const int t = threadIdx.x;
    const int base = t * 64;
    unsigned s = 0;
    for (int j = 0; j < 64; ++j) s += counts[base + j];
    part[t] = s;
    __syncthreads();
    if (t == 0) {
        unsigned run = 0;
        for (int i = 0; i < 1024; ++i) { unsigned v = part[i]; part[i] = run; run += v; }
    }
    __syncthreads();
    unsigned run = part[t];
    for (int j = 0; j < 64; ++j) {
        unsigned c = counts[base + j];
        offs[base + j]   = run;
        cursor[base + j] = run;
        run += c;
    }
    if (t == 1023) offs[PLANE] = run;
}

// Bin taps by output pixel. Entry: {hw:14 | k:2} in low 16, fp16 weight in high 16.
__global__ __launch_bounds__(256) void scatter_kernel(
    const int* __restrict__ sm, const float* __restrict__ iw,
    unsigned* __restrict__ cursor, unsigned* __restrict__ entries)
{
    int r = blockIdx.x * 256 + threadIdx.x;
    if (r >= TAPS) return;
    int o = sm[r];
    unsigned hw = (unsigned)(r >> 4);        // r = ((hw*K)+k)*P + p
    unsigned k  = (unsigned)((r >> 2) & 3);
    __half h = __float2half_rn(iw[r]);
    unsigned short hb; __builtin_memcpy(&hb, &h, 2);
    unsigned pos = atomicAdd(&cursor[o], 1u);
    entries[pos] = hw | (k << 14) | ((unsigned)hb << 16);
}

// ---------------- Main gather kernel: no atomics ----------------
// One 1024-thread block per (b,c). Stage the input plane packed as
// xk = (bits(x) & ~3) | k  (2 mantissa LSBs carry the winning k; ~4e-7 rel err).
// Each thread sums contributor segments for 64 strided outputs -> coalesced stores.
__global__ __launch_bounds__(1024, 8) void unpool_gather_kernel(
    const float* __restrict__ x,
    const int*   __restrict__ idx_mask,
    const unsigned* __restrict__ offs,
    const unsigned* __restrict__ entries,
    float* __restrict__ out)
{
    __shared__ unsigned xk[HW];              // 64 KiB -> 2 blocks/CU, 32 waves/CU

    const int bc = blockIdx.x;
    const float* xp = x + (size_t)bc * HW;
    const int*   ip = idx_mask + (size_t)bc * HW;

    for (int t = threadIdx.x; t < HW; t += 1024) {
        unsigned xb = __float_as_uint(xp[t]);
        xk[t] = (xb & ~3u) | ((unsigned)ip[t] & 3u);
    }
    __syncthreads();

    float* op = out + (size_t)bc * PLANE;
    for (int i = 0; i < PLANE / 1024; ++i) {           // 64 outputs per thread
        const int o = i * 1024 + threadIdx.x;
        unsigned e   = offs[o];
        const unsigned end = offs[o + 1];
        float acc = 0.f;
        for (; e < end; ++e) {
            unsigned ent = entries[e];
            unsigned u   = xk[ent & 0x3fffu];
            if (((u ^ (ent >> 14)) & 3u) == 0u) {      // idx_mask[hw] == k
                float w  = h2f((unsigned short)(ent >> 16));
                float xv = __uint_as_float(u & ~3u);
                acc = fmaf(w, xv, acc);
            }
        }
        op[o] = acc;                                   // coalesced
    }
}

// ---------------- Fallback path (previous verified kernel) ----------------

static __device__ __forceinline__ uint4 sel4(bool c, uint4 a, uint4 b) {
    return make_uint4(c ? a.x : b.x, c ? a.y : b.y, c ? a.z : b.z, c ? a.w : b.w);
}
static __device__ __forceinline__ float2 u2f2(unsigned u) {
    __half2 h; __builtin_memcpy(&h, &u, 4); return __half22float2(h);
}

__global__ __launch_bounds__(256) void compact_table_kernel(
    const int4* __restrict__ sm, const float4* __restrict__ iw, uint4* __restrict__ ct)
{
    int r = blockIdx.x * blockDim.x + threadIdx.x;
    if (r >= HW * K) return;
    int4   s = sm[r];
    float4 w = iw[r];
    uint4 o;
    o.x = ((unsigned)s.x & 0xffffu) | (((unsigned)s.y & 0xffffu) << 16);
    o.y = ((unsigned)s.z & 0xffffu) | (((unsigned)s.w & 0xffffu) << 16);
    __half2 h01 = __floats2half2_rn(w.x, w.y);
    __half2 h23 = __floats2half2_rn(w.z, w.w);
    __builtin_memcpy(&o.z, &h01, 4);
    __builtin_memcpy(&o.w, &h23, 4);
    ct[r] = o;
}

__global__ __launch_bounds__(BLOCK) void unpool_lds2_kernel(
    const float* __restrict__ x,
    const int*   __restrict__ idx_mask,
    const uint4* __restrict__ ct,
    float* __restrict__ out)
{
    __shared__ float acc[QUARTER];

    const int bc    = blockIdx.x >> 2;
    const int q     = blockIdx.x & 3;
    const int qbase = q * QUARTER;

    float4* acc4 = (float4*)acc;
    for (int t = threadIdx.x; t < QUARTER / 4; t += BLOCK)
        acc4[t] = make_float4(0.f, 0.f, 0.f, 0.f);
    __syncthreads();

    const float* xp = x + (size_t)bc * HW;
    const int*   ip = idx_mask + (size_t)bc * HW;

    for (int hw = threadIdx.x; hw < HW; hw += BLOCK) {
        float xv = xp[hw];
        int   k  = ip[hw];
        const uint4* c = ct + (hw << 2);
        uint4 r0 = c[0], r1 = c[1], r2 = c[2], r3 = c[3];
        uint4 rl = sel4(k & 1, r1, r0);
        uint4 rh = sel4(k & 1, r3, r2);
        uint4 r  = sel4(k & 2, rh, rl);

        int i0 = r.x & 0xffff, i1 = (int)(r.x >> 16);
        int i2 = r.y & 0xffff, i3 = (int)(r.y >> 16);
        float2 w01 = u2f2(r.z);
        float2 w23 = u2f2(r.w);

        int a;
        a = i0 - qbase; if ((unsigned)a < (unsigned)QUARTER) atomicAdd(&acc[a], w01.x * xv);
        a = i1 - qbase; if ((unsigned)a < (unsigned)QUARTER) atomicAdd(&acc[a], w01.y * xv);
        a = i2 - qbase; if ((unsigned)a < (unsigned)QUARTER) atomicAdd(&acc[a], w23.x * xv);
        a = i3 - qbase; if ((unsigned)a < (unsigned)QUARTER) atomicAdd(&acc[a], w23.y * xv);
    }
    __syncthreads();

    float4* op4 = (float4*)(out + (size_t)bc * PLANE + qbase);
    for (int t = threadIdx.x; t < QUARTER / 4; t += BLOCK)
        op4[t] = acc4[t];
}

__global__ __launch_bounds__(256) void unpool_lds_fallback_kernel(
    const float* __restrict__ x,
    const int*   __restrict__ idx_mask,
    const int4*  __restrict__ sample_map,
    const float4* __restrict__ interp_w,
    float* __restrict__ out)
{
    __shared__ float acc[QUARTER];
    const int bc    = blockIdx.x >> 2;
    const int q     = blockIdx.x & 3;
    const int qbase = q * QUARTER;
    float4* acc4 = (float4*)acc;
    for (int t = threadIdx.x; t < QUARTER / 4; t += 256)
        acc4[t] = make_float4(0.f, 0.f, 0.f, 0.f);
    __syncthreads();
    const float* xp = x + (size_t)bc * HW;
    const int*   ip = idx_mask + (size_t)bc * HW;
    for (int hw = threadIdx.x; hw < HW; hw += 256) {
        float xv = xp[hw];
        int   k  = ip[hw];
        int row = hw * K + k;
        int4   sel = sample_map[row];
        float4 w   = interp_w[row];
        int a;
        a = sel.x - qbase; if ((unsigned)a < (unsigned)QUARTER) atomicAdd(&acc[a], w.x * xv);
        a = sel.y - qbase; if ((unsigned)a < (unsigned)QUARTER) atomicAdd(&acc[a], w.y * xv);
        a = sel.z - qbase; if ((unsigned)a < (unsigned)QUARTER) atomicAdd(&acc[a], w.z * xv);
        a = sel.w - qbase; if ((unsigned)a < (unsigned)QUARTER) atomicAdd(&acc[a], w.w * xv);
    }
    __syncthreads();
    float4* op4 = (float4*)(out + (size_t)bc * PLANE + qbase);
    for (int t = threadIdx.x; t < QUARTER / 4; t += 256)
        op4[t] = acc4[t];
}

extern "C" void kernel_launch(void* const* d_in, const int* in_sizes, int n_in,
                              void* d_out, int out_size, void* d_ws, size_t ws_size,
                              hipStream_t stream) {
    const float*  x          = (const float*)d_in[0];
    const int*    idx_mask   = (const int*)d_in[1];
    const int*    sample_map = (const int*)d_in[2];
    const float*  interp_w   = (const float*)d_in[3];
    float* out = (float*)d_out;

    if (ws_size >= WS_GATHER_BYTES) {
        unsigned* offs    = (unsigned*)d_ws;
        unsigned* cursor  = offs + OFFS_SLOTS;
        unsigned* counts  = cursor + PLANE;
        unsigned* entries = counts + PLANE;

        zero_counts_kernel<<<PLANE / 256, 256, 0, stream>>>(counts);
        hist_kernel<<<TAPS / 256, 256, 0, stream>>>(sample_map, counts);
        scan_kernel<<<1, 1024, 0, stream>>>(counts, offs, cursor);
        scatter_kernel<<<TAPS / 256, 256, 0, stream>>>(sample_map, interp_w, cursor, entries);
        unpool_gather_kernel<<<B * C, 1024, 0, stream>>>(x, idx_mask, offs, entries, out);
    } else if (ws_size >= TABLE_BYTES) {
        uint4* ct = (uint4*)d_ws;
        compact_table_kernel<<<(HW * K + 255) / 256, 256, 0, stream>>>(
            (const int4*)sample_map, (const float4*)interp_w, ct);
        unpool_lds2_kernel<<<B * C * NQ, BLOCK, 0, stream>>>(
            x, idx_mask, ct, out);
    } else {
        unpool_lds_fallback_kernel<<<B * C * NQ, 256, 0, stream>>>(
            x, idx_mask, (const int4*)sample_map, (const float4*)interp_w, out);
    }
}

// Round 2
// 571.228 us; speedup vs baseline: 1.2384x; 1.2384x over previous
//
#include <hip/hip_runtime.h>
#include <hip/hip_fp16.h>

// Problem constants (from reference setup_inputs)
constexpr int B  = 16;
constexpr int C  = 64;
constexpr int OH = 128;
constexpr int OW = 128;
constexpr int HW = OH * OW;                 // 16384 inputs per (b,c) plane
constexpr int K  = 4;
constexpr int P  = 4;
constexpr int TAPS = HW * K * P;            // 262144 static taps
constexpr int OUT_H = 256;
constexpr int OUT_W = 256;
constexpr int PLANE = OUT_H * OUT_W;        // 65536 outputs per (b,c) plane
constexpr int NQ = 4;                       // quarters (fallback path)
constexpr int QUARTER = PLANE / NQ;
constexpr int BLOCK = 512;
constexpr size_t TABLE_BYTES = (size_t)HW * K * 16;  // 1 MiB compact table (fallback)

// Chunked-gather workspace (u32 slots):
//   desc   : PLANE   (base_chunk | nchunks<<24)
//   cursor : PLANE   (u32-slot write cursor for scatter)
//   counts : PLANE
//   entries: CHUNK_CAP uint4 chunks (4 entries each)
// Sum ceil(N/4) <= (TAPS + 3*PLANE)/4 = 114688 exactly.
constexpr int CHUNK_CAP = 114688;
constexpr size_t WS_CHUNK_BYTES = ((size_t)PLANE * 3) * 4 + (size_t)CHUNK_CAP * 16; // 2.5 MiB

static __device__ __forceinline__ float h2f(unsigned short u) {
    __half h; __builtin_memcpy(&h, &u, 2); return __half2float(h);
}

// ---------------- Chunked-gather pre-pass ----------------

__global__ __launch_bounds__(256) void zero_ws_kernel(
    unsigned* __restrict__ counts, uint4* __restrict__ entries)
{
    int r = blockIdx.x * 256 + threadIdx.x;
    if (r < PLANE)     counts[r]  = 0u;
    if (r < CHUNK_CAP) entries[r] = make_uint4(0u, 0u, 0u, 0u);
}

__global__ __launch_bounds__(256) void hist_kernel(
    const int* __restrict__ sm, unsigned* __restrict__ counts)
{
    int r = blockIdx.x * 256 + threadIdx.x;
    if (r < TAPS) atomicAdd(&counts[sm[r]], 1u);
}

// Parallel exclusive scan over per-output CHUNK counts (ceil(N/4)).
// Produces desc[o] = chunk_base | (nchunks<<24) and cursor[o] = chunk_base*4.
__global__ __launch_bounds__(1024) void scan_chunks_kernel(
    const unsigned* __restrict__ counts,
    unsigned* __restrict__ desc, unsigned* __restrict__ cursor)
{
    __shared__ unsigned part[1024];
    const int t = threadIdx.x;
    const int base = t * 64;
    unsigned s = 0;
    for (int j = 0; j < 64; ++j) s += (counts[base + j] + 3u) >> 2;
    part[t] = s;
    __syncthreads();
    // Hillis-Steele inclusive scan over 1024 partials
    for (int st = 1; st < 1024; st <<= 1) {
        unsigned v = (t >= st) ? part[t - st] : 0u;
        __syncthreads();
        part[t] += v;
        __syncthreads();
    }
    unsigned run = part[t] - s;   // exclusive base for this thread's span
    for (int j = 0; j < 64; ++j) {
        unsigned c   = counts[base + j];
        unsigned nch = (c + 3u) >> 2;
        desc[base + j]   = run | (nch << 24);
        cursor[base + j] = run * 4u;          // entry-slot units
        run += nch;
    }
}

// Bin taps by output. Entry: bits[1:0]=k, bits[15:2]=hw<<2 (pre-scaled LDS
// byte addr), bits[31:16]=fp16 weight.  r = hw*16 + k*4 + p.
__global__ __launch_bounds__(256) void scatter_chunks_kernel(
    const int* __restrict__ sm, const float* __restrict__ iw,
    unsigned* __restrict__ cursor, unsigned* __restrict__ entries_u32)
{
    int r = blockIdx.x * 256 + threadIdx.x;
    if (r >= TAPS) return;
    int o = sm[r];
    unsigned hw = (unsigned)(r >> 4);
    unsigned k  = (unsigned)((r >> 2) & 3);
    __half h = __float2half_rn(iw[r]);
    unsigned short hb; __builtin_memcpy(&hb, &h, 2);
    unsigned ent = (hw << 2) | k | ((unsigned)hb << 16);
    unsigned pos = atomicAdd(&cursor[o], 1u);
    entries_u32[pos] = ent;
}

// ---------------- Main chunked-gather kernel: no atomics ----------------
// One 1024-thread block per (b,c). LDS holds xk[hw] = (bits(x) & ~3) | k.
// Each thread sums 64 strided outputs; contributors come 4-per-uint4 chunk.
__global__ __launch_bounds__(1024, 8) void unpool_chunk_kernel(
    const float* __restrict__ x,
    const int*   __restrict__ idx_mask,
    const unsigned* __restrict__ desc,
    const uint4* __restrict__ entries,
    float* __restrict__ out)
{
    __shared__ unsigned xk[HW];              // 64 KiB -> 2 blocks/CU, 32 waves/CU

    const int bc = blockIdx.x;
    const float4* xp4 = (const float4*)(x + (size_t)bc * HW);
    const int4*   ip4 = (const int4*)(idx_mask + (size_t)bc * HW);
    uint4* xk4 = (uint4*)xk;

    for (int t = threadIdx.x; t < HW / 4; t += 1024) {
        float4 xv = xp4[t];
        int4   kv = ip4[t];
        uint4 o;
        o.x = (__float_as_uint(xv.x) & ~3u) | ((unsigned)kv.x & 3u);
        o.y = (__float_as_uint(xv.y) & ~3u) | ((unsigned)kv.y & 3u);
        o.z = (__float_as_uint(xv.z) & ~3u) | ((unsigned)kv.z & 3u);
        o.w = (__float_as_uint(xv.w) & ~3u) | ((unsigned)kv.w & 3u);
        xk4[t] = o;
    }
    __syncthreads();

    const char* xkb = (const char*)xk;
    float* op = out + (size_t)bc * PLANE;

    for (int i = 0; i < PLANE / 1024; ++i) {           // 64 outputs per thread
        const int o = i * 1024 + threadIdx.x;
        const unsigned d   = desc[o];
        const unsigned nch = d >> 24;
        const uint4* ep = entries + (d & 0xffffffu);
        float acc = 0.f;
        for (unsigned j = 0; j < nch; ++j) {
            uint4 ch = ep[j];
            {   unsigned e = ch.x;
                unsigned u = *(const unsigned*)(xkb + (e & 0xfffcu));
                float w = (((u ^ e) & 3u) == 0u) ? h2f((unsigned short)(e >> 16)) : 0.f;
                acc = fmaf(w, __uint_as_float(u & ~3u), acc); }
            {   unsigned e = ch.y;
                unsigned u = *(const unsigned*)(xkb + (e & 0xfffcu));
                float w = (((u ^ e) & 3u) == 0u) ? h2f((unsigned short)(e >> 16)) : 0.f;
                acc = fmaf(w, __uint_as_float(u & ~3u), acc); }
            {   unsigned e = ch.z;
                unsigned u = *(const unsigned*)(xkb + (e & 0xfffcu));
                float w = (((u ^ e) & 3u) == 0u) ? h2f((unsigned short)(e >> 16)) : 0.f;
                acc = fmaf(w, __uint_as_float(u & ~3u), acc); }
            {   unsigned e = ch.w;
                unsigned u = *(const unsigned*)(xkb + (e & 0xfffcu));
                float w = (((u ^ e) & 3u) == 0u) ? h2f((unsigned short)(e >> 16)) : 0.f;
                acc = fmaf(w, __uint_as_float(u & ~3u), acc); }
        }
        op[o] = acc;                                   // coalesced
    }
}

// ---------------- Fallback paths (previous verified kernels) ----------------

static __device__ __forceinline__ uint4 sel4(bool c, uint4 a, uint4 b) {
    return make_uint4(c ? a.x : b.x, c ? a.y : b.y, c ? a.z : b.z, c ? a.w : b.w);
}
static __device__ __forceinline__ float2 u2f2(unsigned u) {
    __half2 h; __builtin_memcpy(&h, &u, 4); return __half22float2(h);
}

__global__ __launch_bounds__(256) void compact_table_kernel(
    const int4* __restrict__ sm, const float4* __restrict__ iw, uint4* __restrict__ ct)
{
    int r = blockIdx.x * blockDim.x + threadIdx.x;
    if (r >= HW * K) return;
    int4   s = sm[r];
    float4 w = iw[r];
    uint4 o;
    o.x = ((unsigned)s.x & 0xffffu) | (((unsigned)s.y & 0xffffu) << 16);
    o.y = ((unsigned)s.z & 0xffffu) | (((unsigned)s.w & 0xffffu) << 16);
    __half2 h01 = __floats2half2_rn(w.x, w.y);
    __half2 h23 = __floats2half2_rn(w.z, w.w);
    __builtin_memcpy(&o.z, &h01, 4);
    __builtin_memcpy(&o.w, &h23, 4);
    ct[r] = o;
}

__global__ __launch_bounds__(BLOCK) void unpool_lds2_kernel(
    const float* __restrict__ x,
    const int*   __restrict__ idx_mask,
    const uint4* __restrict__ ct,
    float* __restrict__ out)
{
    __shared__ float acc[QUARTER];

    const int bc    = blockIdx.x >> 2;
    const int q     = blockIdx.x & 3;
    const int qbase = q * QUARTER;

    float4* acc4 = (float4*)acc;
    for (int t = threadIdx.x; t < QUARTER / 4; t += BLOCK)
        acc4[t] = make_float4(0.f, 0.f, 0.f, 0.f);
    __syncthreads();

    const float* xp = x + (size_t)bc * HW;
    const int*   ip = idx_mask + (size_t)bc * HW;

    for (int hw = threadIdx.x; hw < HW; hw += BLOCK) {
        float xv = xp[hw];
        int   k  = ip[hw];
        const uint4* c = ct + (hw << 2);
        uint4 r0 = c[0], r1 = c[1], r2 = c[2], r3 = c[3];
        uint4 rl = sel4(k & 1, r1, r0);
        uint4 rh = sel4(k & 1, r3, r2);
        uint4 r  = sel4(k & 2, rh, rl);

        int i0 = r.x & 0xffff, i1 = (int)(r.x >> 16);
        int i2 = r.y & 0xffff, i3 = (int)(r.y >> 16);
        float2 w01 = u2f2(r.z);
        float2 w23 = u2f2(r.w);

        int a;
        a = i0 - qbase; if ((unsigned)a < (unsigned)QUARTER) atomicAdd(&acc[a], w01.x * xv);
        a = i1 - qbase; if ((unsigned)a < (unsigned)QUARTER) atomicAdd(&acc[a], w01.y * xv);
        a = i2 - qbase; if ((unsigned)a < (unsigned)QUARTER) atomicAdd(&acc[a], w23.x * xv);
        a = i3 - qbase; if ((unsigned)a < (unsigned)QUARTER) atomicAdd(&acc[a], w23.y * xv);
    }
    __syncthreads();

    float4* op4 = (float4*)(out + (size_t)bc * PLANE + qbase);
    for (int t = threadIdx.x; t < QUARTER / 4; t += BLOCK)
        op4[t] = acc4[t];
}

__global__ __launch_bounds__(256) void unpool_lds_fallback_kernel(
    const float* __restrict__ x,
    const int*   __restrict__ idx_mask,
    const int4*  __restrict__ sample_map,
    const float4* __restrict__ interp_w,
    float* __restrict__ out)
{
    __shared__ float acc[QUARTER];
    const int bc    = blockIdx.x >> 2;
    const int q     = blockIdx.x & 3;
    const int qbase = q * QUARTER;
    float4* acc4 = (float4*)acc;
    for (int t = threadIdx.x; t < QUARTER / 4; t += 256)
        acc4[t] = make_float4(0.f, 0.f, 0.f, 0.f);
    __syncthreads();
    const float* xp = x + (size_t)bc * HW;
    const int*   ip = idx_mask + (size_t)bc * HW;
    for (int hw = threadIdx.x; hw < HW; hw += 256) {
        float xv = xp[hw];
        int   k  = ip[hw];
        int row = hw * K + k;
        int4   sel = sample_map[row];
        float4 w   = interp_w[row];
        int a;
        a = sel.x - qbase; if ((unsigned)a < (unsigned)QUARTER) atomicAdd(&acc[a], w.x * xv);
        a = sel.y - qbase; if ((unsigned)a < (unsigned)QUARTER) atomicAdd(&acc[a], w.y * xv);
        a = sel.z - qbase; if ((unsigned)a < (unsigned)QUARTER) atomicAdd(&acc[a], w.z * xv);
        a = sel.w - qbase; if ((unsigned)a < (unsigned)QUARTER) atomicAdd(&acc[a], w.w * xv);
    }
    __syncthreads();
    float4* op4 = (float4*)(out + (size_t)bc * PLANE + qbase);
    for (int t = threadIdx.x; t < QUARTER / 4; t += 256)
        op4[t] = acc4[t];
}

extern "C" void kernel_launch(void* const* d_in, const int* in_sizes, int n_in,
                              void* d_out, int out_size, void* d_ws, size_t ws_size,
                              hipStream_t stream) {
    const float*  x          = (const float*)d_in[0];
    const int*    idx_mask   = (const int*)d_in[1];
    const int*    sample_map = (const int*)d_in[2];
    const float*  interp_w   = (const float*)d_in[3];
    float* out = (float*)d_out;

    if (ws_size >= WS_CHUNK_BYTES) {
        unsigned* desc    = (unsigned*)d_ws;
        unsigned* cursor  = desc + PLANE;
        unsigned* counts  = cursor + PLANE;
        uint4*    entries = (uint4*)(counts + PLANE);

        zero_ws_kernel<<<(CHUNK_CAP + 255) / 256, 256, 0, stream>>>(counts, entries);
        hist_kernel<<<TAPS / 256, 256, 0, stream>>>(sample_map, counts);
        scan_chunks_kernel<<<1, 1024, 0, stream>>>(counts, desc, cursor);
        scatter_chunks_kernel<<<TAPS / 256, 256, 0, stream>>>(
            sample_map, interp_w, cursor, (unsigned*)entries);
        unpool_chunk_kernel<<<B * C, 1024, 0, stream>>>(x, idx_mask, desc, entries, out);
    } else if (ws_size >= TABLE_BYTES) {
        uint4* ct = (uint4*)d_ws;
        compact_table_kernel<<<(HW * K + 255) / 256, 256, 0, stream>>>(
            (const int4*)sample_map, (const float4*)interp_w, ct);
        unpool_lds2_kernel<<<B * C * NQ, BLOCK, 0, stream>>>(
            x, idx_mask, ct, out);
    } else {
        unpool_lds_fallback_kernel<<<B * C * NQ, 256, 0, stream>>>(
            x, idx_mask, (const int4*)sample_map, (const float4*)interp_w, out);
    }
}